// Round 1
// baseline (53.928 us; speedup 1.0000x reference)
//
#include <hip/hip_runtime.h>
#include <hip/hip_bf16.h>

// YOLO loss (forward only). One thread per (n, s, s) cell.
// pred: [N,7,7,20] f32 contiguous -> 80 B/cell, 16B-aligned (80 = 5*16).
// tgt : [N,7,7,6]  f32 contiguous -> 24 B/cell, 8B-aligned.
// Output: scalar f32 = total / N.

#define SBLK 256

constexpr float L_COORD = 5.0f;
constexpr float L_NOOBJ = 0.5f;
constexpr float EPS_    = 1e-6f;

__device__ __forceinline__ float iou_f(float l1l, float l1t, float w1, float h1,
                                       float l2l, float l2t, float w2, float h2) {
    float l1r = l1l + w1, l1b = l1t + h1;
    float l2r = l2l + w2, l2b = l2t + h2;
    float a1 = w1 * h1, a2 = w2 * h2;
    bool cont_by2 = (l2l <= l1l) && (l2t <= l1t) && (l2r >= l1r) && (l2b >= l1b);
    bool cont_by1 = (l1l <= l2l) && (l1t <= l2t) && (l1r >= l2r) && (l1b >= l2b);
    bool sep = (l1r <= l2l) || (l2r <= l1l) || (l1b <= l2t) || (l2b <= l1t);
    float iw = fminf(l1r, l2r) - fmaxf(l1l, l2l);
    float ih = fminf(l1b, l2b) - fmaxf(l1t, l2t);
    float inter = iw * ih;
    float gen = inter / (a1 + a2 - inter);   // IEEE div (no fast-math flag)
    float r = sep ? 0.0f : gen;
    r = cont_by1 ? (a2 / a1) : r;
    r = cont_by2 ? (a1 / a2) : r;            // outermost where wins
    return r;
}

__device__ __forceinline__ float clamp01(float x) { return fminf(fmaxf(x, 0.0f), 1.0f); }

__global__ __launch_bounds__(SBLK) void yolo_loss_kernel(
        const float* __restrict__ pred, const float* __restrict__ tgt,
        double* __restrict__ acc, int ncells) {
    int i = blockIdx.x * SBLK + threadIdx.x;
    float total = 0.0f;
    if (i < ncells) {
        const float4* p4 = reinterpret_cast<const float4*>(pred + (size_t)i * 20);
        float4 pa = p4[0];  // pred[0..3]
        float4 pb = p4[1];  // pred[4..7]
        float4 pc = p4[2];  // pred[8..11]
        float4 pd = p4[3];  // pred[12..15]
        float4 pe = p4[4];  // pred[16..19]
        const float2* t2 = reinterpret_cast<const float2*>(tgt + (size_t)i * 6);
        float2 t0 = t2[0];  // tgt[0..1] (left, top)
        float2 t1 = t2[1];  // tgt[2..3] (w, h)
        float2 tc = t2[2];  // tgt[4..5] (conf, cls)

        float conf = tc.x;
        float coo = (conf > 0.0f) ? 1.0f : 0.0f;
        float noo = (conf == 0.0f) ? 1.0f : 0.0f;

        // noobj loss (pred[4], pred[9])
        float d0 = pb.x - conf, d1 = pc.y - conf;
        float noobj = noo * (d0 * d0 + d1 * d1);

        // boxes: bp0 = pred[0:5], bp1 = pred[5:10], bt = tgt[0:4]
        float b0l = pa.x, b0t = pa.y, b0w = pa.z, b0h = pa.w, b0c = pb.x;
        float b1l = pb.y, b1t = pb.z, b1w = pb.w, b1h = pc.x, b1c = pc.y;
        float btl = t0.x, btt = t0.y, btw = t1.x, bth = t1.y;

        float iou0 = iou_f(b0l, b0t, b0w, b0h, btl, btt, btw, bth);
        float iou1 = iou_f(b1l, b1t, b1w, b1h, btl, btt, btw, bth);
        bool pick0 = (iou0 >= iou1);
        float max_iou = pick0 ? iou0 : iou1;

        float rl = pick0 ? b0l : b1l;
        float rt = pick0 ? b0t : b1t;
        float rw = pick0 ? b0w : b1w;
        float rh = pick0 ? b0h : b1h;
        float rc = pick0 ? b0c : b1c;
        float nc = pick0 ? b1c : b0c;   // non-responsible confidence

        float cd = rc - max_iou;
        float contain = cd * cd;
        float not_contain = nc * nc;

        // localization loss
        float ex = clamp01(rl) - clamp01(btl);
        float ey = clamp01(rt) - clamp01(btt);
        float sw = sqrtf(fminf(fmaxf(rw, EPS_), 1.0f)) - sqrtf(fminf(fmaxf(btw, EPS_), 1.0f));
        float sh = sqrtf(fminf(fmaxf(rh, EPS_), 1.0f)) - sqrtf(fminf(fmaxf(bth, EPS_), 1.0f));
        float loc = ex * ex + ey * ey + sw * sw + sh * sh;

        // class loss: logsumexp(logits) - logits[cls]
        float lg0 = pc.z, lg1 = pc.w;
        float lg2 = pd.x, lg3 = pd.y, lg4 = pd.z, lg5 = pd.w;
        float lg6 = pe.x, lg7 = pe.y, lg8 = pe.z, lg9 = pe.w;
        float m = fmaxf(lg0, lg1);
        m = fmaxf(m, fmaxf(lg2, lg3));
        m = fmaxf(m, fmaxf(lg4, lg5));
        m = fmaxf(m, fmaxf(lg6, lg7));
        m = fmaxf(m, fmaxf(lg8, lg9));
        float ssum = __expf(lg0 - m) + __expf(lg1 - m) + __expf(lg2 - m) +
                     __expf(lg3 - m) + __expf(lg4 - m) + __expf(lg5 - m) +
                     __expf(lg6 - m) + __expf(lg7 - m) + __expf(lg8 - m) +
                     __expf(lg9 - m);
        float logz = m + __logf(ssum);
        int ci = (int)tc.y;
        float picked = lg0;
        picked = (ci == 1) ? lg1 : picked;
        picked = (ci == 2) ? lg2 : picked;
        picked = (ci == 3) ? lg3 : picked;
        picked = (ci == 4) ? lg4 : picked;
        picked = (ci == 5) ? lg5 : picked;
        picked = (ci == 6) ? lg6 : picked;
        picked = (ci == 7) ? lg7 : picked;
        picked = (ci == 8) ? lg8 : picked;
        picked = (ci == 9) ? lg9 : picked;
        float cls_loss = logz - picked;

        total = L_COORD * (coo * loc)
              + 2.0f * (coo * contain)
              + (coo * not_contain)
              + L_NOOBJ * noobj
              + coo * cls_loss;
    }

    // reduce: wave(64) shuffle in double -> LDS -> one atomicAdd per block
    double v = (double)total;
    #pragma unroll
    for (int off = 32; off > 0; off >>= 1)
        v += __shfl_down(v, off, 64);
    __shared__ double sm[SBLK / 64];
    int lane = threadIdx.x & 63;
    int wid  = threadIdx.x >> 6;
    if (lane == 0) sm[wid] = v;
    __syncthreads();
    if (threadIdx.x == 0) {
        double s = 0.0;
        #pragma unroll
        for (int w = 0; w < SBLK / 64; ++w) s += sm[w];
        atomicAdd(acc, s);
    }
}

__global__ void yolo_finalize_kernel(const double* __restrict__ acc,
                                     float* __restrict__ out, double invN) {
    out[0] = (float)(acc[0] * invN);
}

extern "C" void kernel_launch(void* const* d_in, const int* in_sizes, int n_in,
                              void* d_out, int out_size, void* d_ws, size_t ws_size,
                              hipStream_t stream) {
    const float* pred = (const float*)d_in[0];
    const float* tgt  = (const float*)d_in[1];
    int ncells = in_sizes[0] / 20;          // N*7*7
    int N = ncells / 49;

    hipMemsetAsync(d_ws, 0, sizeof(double), stream);
    int nblocks = (ncells + SBLK - 1) / SBLK;
    yolo_loss_kernel<<<nblocks, SBLK, 0, stream>>>(pred, tgt, (double*)d_ws, ncells);
    yolo_finalize_kernel<<<1, 1, 0, stream>>>((const double*)d_ws, (float*)d_out, 1.0 / (double)N);
}

// Round 2
// 21.787 us; speedup vs baseline: 2.4752x; 2.4752x over previous
//
#include <hip/hip_runtime.h>
#include <hip/hip_bf16.h>

// YOLO loss (forward only). One thread per (n, s, s) cell.
// pred: [N,7,7,20] f32 contiguous -> 80 B/cell, 16B-aligned (80 = 5*16).
// tgt : [N,7,7,6]  f32 contiguous -> 24 B/cell, 8B-aligned.
// Output: scalar f32 = total / N.
//
// R2: removed the single-address f64 atomicAdd (3136 serialized cross-XCD
// RMWs ~= the 40us stall). Blocks store partials to d_ws; kernel 2 reduces.

#define SBLK 256

constexpr float L_COORD = 5.0f;
constexpr float L_NOOBJ = 0.5f;
constexpr float EPS_    = 1e-6f;

__device__ __forceinline__ float iou_f(float l1l, float l1t, float w1, float h1,
                                       float l2l, float l2t, float w2, float h2) {
    float l1r = l1l + w1, l1b = l1t + h1;
    float l2r = l2l + w2, l2b = l2t + h2;
    float a1 = w1 * h1, a2 = w2 * h2;
    bool cont_by2 = (l2l <= l1l) && (l2t <= l1t) && (l2r >= l1r) && (l2b >= l1b);
    bool cont_by1 = (l1l <= l2l) && (l1t <= l2t) && (l1r >= l2r) && (l1b >= l2b);
    bool sep = (l1r <= l2l) || (l2r <= l1l) || (l1b <= l2t) || (l2b <= l1t);
    float iw = fminf(l1r, l2r) - fmaxf(l1l, l2l);
    float ih = fminf(l1b, l2b) - fmaxf(l1t, l2t);
    float inter = iw * ih;
    float gen = inter / (a1 + a2 - inter);   // IEEE div (no fast-math flag)
    float r = sep ? 0.0f : gen;
    r = cont_by1 ? (a2 / a1) : r;
    r = cont_by2 ? (a1 / a2) : r;            // outermost where wins
    return r;
}

__device__ __forceinline__ float clamp01(float x) { return fminf(fmaxf(x, 0.0f), 1.0f); }

__global__ __launch_bounds__(SBLK) void yolo_loss_kernel(
        const float* __restrict__ pred, const float* __restrict__ tgt,
        double* __restrict__ partials, int ncells) {
    int i = blockIdx.x * SBLK + threadIdx.x;
    float total = 0.0f;
    if (i < ncells) {
        const float4* p4 = reinterpret_cast<const float4*>(pred + (size_t)i * 20);
        float4 pa = p4[0];  // pred[0..3]
        float4 pb = p4[1];  // pred[4..7]
        float4 pc = p4[2];  // pred[8..11]
        float4 pd = p4[3];  // pred[12..15]
        float4 pe = p4[4];  // pred[16..19]
        const float2* t2 = reinterpret_cast<const float2*>(tgt + (size_t)i * 6);
        float2 t0 = t2[0];  // tgt[0..1] (left, top)
        float2 t1 = t2[1];  // tgt[2..3] (w, h)
        float2 tc = t2[2];  // tgt[4..5] (conf, cls)

        float conf = tc.x;
        float coo = (conf > 0.0f) ? 1.0f : 0.0f;
        float noo = (conf == 0.0f) ? 1.0f : 0.0f;

        // noobj loss (pred[4], pred[9])
        float d0 = pb.x - conf, d1 = pc.y - conf;
        float noobj = noo * (d0 * d0 + d1 * d1);

        // boxes: bp0 = pred[0:5], bp1 = pred[5:10], bt = tgt[0:4]
        float b0l = pa.x, b0t = pa.y, b0w = pa.z, b0h = pa.w, b0c = pb.x;
        float b1l = pb.y, b1t = pb.z, b1w = pb.w, b1h = pc.x, b1c = pc.y;
        float btl = t0.x, btt = t0.y, btw = t1.x, bth = t1.y;

        float iou0 = iou_f(b0l, b0t, b0w, b0h, btl, btt, btw, bth);
        float iou1 = iou_f(b1l, b1t, b1w, b1h, btl, btt, btw, bth);
        bool pick0 = (iou0 >= iou1);
        float max_iou = pick0 ? iou0 : iou1;

        float rl = pick0 ? b0l : b1l;
        float rt = pick0 ? b0t : b1t;
        float rw = pick0 ? b0w : b1w;
        float rh = pick0 ? b0h : b1h;
        float rc = pick0 ? b0c : b1c;
        float nc = pick0 ? b1c : b0c;   // non-responsible confidence

        float cd = rc - max_iou;
        float contain = cd * cd;
        float not_contain = nc * nc;

        // localization loss
        float ex = clamp01(rl) - clamp01(btl);
        float ey = clamp01(rt) - clamp01(btt);
        float sw = sqrtf(fminf(fmaxf(rw, EPS_), 1.0f)) - sqrtf(fminf(fmaxf(btw, EPS_), 1.0f));
        float sh = sqrtf(fminf(fmaxf(rh, EPS_), 1.0f)) - sqrtf(fminf(fmaxf(bth, EPS_), 1.0f));
        float loc = ex * ex + ey * ey + sw * sw + sh * sh;

        // class loss: logsumexp(logits) - logits[cls]
        float lg0 = pc.z, lg1 = pc.w;
        float lg2 = pd.x, lg3 = pd.y, lg4 = pd.z, lg5 = pd.w;
        float lg6 = pe.x, lg7 = pe.y, lg8 = pe.z, lg9 = pe.w;
        float m = fmaxf(lg0, lg1);
        m = fmaxf(m, fmaxf(lg2, lg3));
        m = fmaxf(m, fmaxf(lg4, lg5));
        m = fmaxf(m, fmaxf(lg6, lg7));
        m = fmaxf(m, fmaxf(lg8, lg9));
        float ssum = __expf(lg0 - m) + __expf(lg1 - m) + __expf(lg2 - m) +
                     __expf(lg3 - m) + __expf(lg4 - m) + __expf(lg5 - m) +
                     __expf(lg6 - m) + __expf(lg7 - m) + __expf(lg8 - m) +
                     __expf(lg9 - m);
        float logz = m + __logf(ssum);
        int ci = (int)tc.y;
        float picked = lg0;
        picked = (ci == 1) ? lg1 : picked;
        picked = (ci == 2) ? lg2 : picked;
        picked = (ci == 3) ? lg3 : picked;
        picked = (ci == 4) ? lg4 : picked;
        picked = (ci == 5) ? lg5 : picked;
        picked = (ci == 6) ? lg6 : picked;
        picked = (ci == 7) ? lg7 : picked;
        picked = (ci == 8) ? lg8 : picked;
        picked = (ci == 9) ? lg9 : picked;
        float cls_loss = logz - picked;

        total = L_COORD * (coo * loc)
              + 2.0f * (coo * contain)
              + (coo * not_contain)
              + L_NOOBJ * noobj
              + coo * cls_loss;
    }

    // reduce: wave(64) shuffle in double -> LDS -> ONE plain store per block
    double v = (double)total;
    #pragma unroll
    for (int off = 32; off > 0; off >>= 1)
        v += __shfl_down(v, off, 64);
    __shared__ double sm[SBLK / 64];
    int lane = threadIdx.x & 63;
    int wid  = threadIdx.x >> 6;
    if (lane == 0) sm[wid] = v;
    __syncthreads();
    if (threadIdx.x == 0) {
        double s = 0.0;
        #pragma unroll
        for (int w = 0; w < SBLK / 64; ++w) s += sm[w];
        partials[blockIdx.x] = s;   // no atomic: unique slot per block
    }
}

#define RBLK 1024

__global__ __launch_bounds__(RBLK) void yolo_reduce_kernel(
        const double* __restrict__ partials, int nparts,
        float* __restrict__ out, double invN) {
    double v = 0.0;
    for (int idx = threadIdx.x; idx < nparts; idx += RBLK)
        v += partials[idx];
    #pragma unroll
    for (int off = 32; off > 0; off >>= 1)
        v += __shfl_down(v, off, 64);
    __shared__ double sm[RBLK / 64];
    int lane = threadIdx.x & 63;
    int wid  = threadIdx.x >> 6;
    if (lane == 0) sm[wid] = v;
    __syncthreads();
    if (threadIdx.x == 0) {
        double s = 0.0;
        #pragma unroll
        for (int w = 0; w < RBLK / 64; ++w) s += sm[w];
        out[0] = (float)(s * invN);
    }
}

extern "C" void kernel_launch(void* const* d_in, const int* in_sizes, int n_in,
                              void* d_out, int out_size, void* d_ws, size_t ws_size,
                              hipStream_t stream) {
    const float* pred = (const float*)d_in[0];
    const float* tgt  = (const float*)d_in[1];
    int ncells = in_sizes[0] / 20;          // N*7*7
    int N = ncells / 49;

    int nblocks = (ncells + SBLK - 1) / SBLK;
    yolo_loss_kernel<<<nblocks, SBLK, 0, stream>>>(pred, tgt, (double*)d_ws, ncells);
    yolo_reduce_kernel<<<1, RBLK, 0, stream>>>((const double*)d_ws, nblocks,
                                               (float*)d_out, 1.0 / (double)N);
}